// Round 12
// baseline (277.641 us; speedup 1.0000x reference)
//
#include <hip/hip_runtime.h>
#include <math.h>

#define H_DIM 128
#define OUT_DIM 10

typedef __attribute__((ext_vector_type(8))) __bf16 bf16x8;
typedef __attribute__((ext_vector_type(8))) unsigned short ushort8;
typedef __attribute__((ext_vector_type(4))) float f32x4;

__device__ inline unsigned short f2bf_rne(float f) {
    unsigned int u = __float_as_uint(f);
    unsigned int r = u + 0x7FFFu + ((u >> 16) & 1u);
    return (unsigned short)(r >> 16);
}
__device__ inline float bf_lo(unsigned int u) { return __uint_as_float(u << 16); }
__device__ inline float bf_hi(unsigned int u) { return __uint_as_float(u & 0xFFFF0000u); }

// ---------------------------------------------------------------------------
// Fused prep: [0,128) W1+W2 split/transpose; [128,128+xb) X split;
// [128+xb, ...) edge histogram (cnt zeroed by preceding memset).
__global__ __launch_bounds__(256) void prep_kernel(const float* __restrict__ W1,
                                                   const float* __restrict__ W2,
                                                   unsigned short* __restrict__ Wt1Hi,
                                                   unsigned short* __restrict__ Wt1Lo,
                                                   unsigned short* __restrict__ Wt2Hi,
                                                   unsigned short* __restrict__ Wt2Lo,
                                                   const float* __restrict__ X,
                                                   unsigned short* __restrict__ Xhi,
                                                   unsigned short* __restrict__ Xlo,
                                                   int total8, int xb,
                                                   const int* __restrict__ col,
                                                   int* __restrict__ cnt, int E) {
    if (blockIdx.x < 128) {
        int i = blockIdx.x * 256 + threadIdx.x;   // 0..32767
        const float* src   = (i < 16384) ? W1    : W2;
        unsigned short* dh = (i < 16384) ? Wt1Hi : Wt2Hi;
        unsigned short* dl = (i < 16384) ? Wt1Lo : Wt2Lo;
        int idx = i & 16383;
        int k = idx >> 7, n = idx & 127;
        float v = src[idx];                        // W[k][n]
        unsigned short hb = f2bf_rne(v);
        float hf = __uint_as_float((unsigned int)hb << 16);
        unsigned short lb = f2bf_rne(v - hf);
        dh[n * H_DIM + k] = hb;
        dl[n * H_DIM + k] = lb;
    } else if (blockIdx.x < 128 + xb) {
        int i = (blockIdx.x - 128) * 256 + threadIdx.x;
        if (i >= total8) return;
        const float* p = X + (size_t)i * 8;
        f32x4 a = *(const f32x4*)p;
        f32x4 b = *(const f32x4*)(p + 4);
        float v[8] = {a.x, a.y, a.z, a.w, b.x, b.y, b.z, b.w};
        ushort8 h, l;
        #pragma unroll
        for (int j = 0; j < 8; ++j) {
            unsigned short hb = f2bf_rne(v[j]);
            float hf = __uint_as_float((unsigned int)hb << 16);
            h[j] = hb;
            l[j] = f2bf_rne(v[j] - hf);
        }
        *(ushort8*)(Xhi + (size_t)i * 8) = h;
        *(ushort8*)(Xlo + (size_t)i * 8) = l;
    } else {
        int e = (blockIdx.x - 128 - xb) * 256 + threadIdx.x;
        if (e < E) atomicAdd(&cnt[col[e]], 1);
    }
}

// ---------------------------------------------------------------------------
// Hierarchical 3-phase scan (proven; single-pass lookback regressed — cross-
// XCD atomic spin chains are an anti-pattern).  Phase1 also computes dinv.
__global__ __launch_bounds__(256) void scan_phase1(const int* __restrict__ cnt,
                                                   int* __restrict__ blockSums,
                                                   float* __restrict__ dinv, int N) {
    __shared__ int red[256];
    int base = blockIdx.x * 1024;
    int t = threadIdx.x;
    int s = 0;
    for (int i = 0; i < 4; ++i) {
        int idx = base + t * 4 + i;
        if (idx < N) {
            int cv = cnt[idx];
            s += cv;
            dinv[idx] = rsqrtf((float)cv + 1.0f);   // deg>=1 (self loop)
        }
    }
    red[t] = s;
    __syncthreads();
    for (int d = 128; d > 0; d >>= 1) {
        if (t < d) red[t] += red[t + d];
        __syncthreads();
    }
    if (t == 0) blockSums[blockIdx.x] = red[0];
}

__global__ __launch_bounds__(256) void scan_phase2(const int* __restrict__ blockSums,
                                                   int* __restrict__ blockOffs,
                                                   int* __restrict__ offs, int B, int N) {
    __shared__ int sh[256];
    int t = threadIdx.x;
    sh[t] = (t < B) ? blockSums[t] : 0;
    __syncthreads();
    for (int d = 1; d < 256; d <<= 1) {
        int v = (t >= d) ? sh[t - d] : 0;
        __syncthreads();
        sh[t] += v;
        __syncthreads();
    }
    if (t < B) blockOffs[t] = (t == 0) ? 0 : sh[t - 1];
    if (t == 255) offs[N] = sh[255];   // == E
}

__global__ __launch_bounds__(256) void scan_phase3(const int* __restrict__ cnt,
                                                   const int* __restrict__ blockOffs,
                                                   int* __restrict__ offs,
                                                   int* __restrict__ cursor, int N) {
    __shared__ int red[256];
    int base = blockIdx.x * 1024;
    int t = threadIdx.x;
    int v[4];
    int s = 0;
    for (int i = 0; i < 4; ++i) {
        int idx = base + t * 4 + i;
        v[i] = (idx < N) ? cnt[idx] : 0;
        s += v[i];
    }
    red[t] = s;
    __syncthreads();
    for (int d = 1; d < 256; d <<= 1) {   // inclusive Hillis-Steele
        int x = (t >= d) ? red[t - d] : 0;
        __syncthreads();
        red[t] += x;
        __syncthreads();
    }
    int run = blockOffs[blockIdx.x] + ((t == 0) ? 0 : red[t - 1]);
    for (int i = 0; i < 4; ++i) {
        int idx = base + t * 4 + i;
        if (idx < N) { offs[idx] = run; cursor[idx] = run; run += v[i]; }
    }
}

// ---------------------------------------------------------------------------
// Scatter, 4 edges/thread: int4 edge loads, 4 INDEPENDENT atomics in flight
// (R11 theory: scatter was dependent-chain latency-bound at 1 atomic/thread).
__global__ __launch_bounds__(256) void scatter_kernel(const int* __restrict__ row,
                                                      const int* __restrict__ col,
                                                      const float* __restrict__ dinv,
                                                      int* __restrict__ cursor,
                                                      int2* __restrict__ csr, int E) {
    int i = blockIdx.x * 256 + threadIdx.x;
    int base = i * 4;
    if (base + 3 < E) {
        int4 r4 = *(const int4*)(row + base);
        int4 c4 = *(const int4*)(col + base);
        float dr0 = dinv[r4.x], dr1 = dinv[r4.y], dr2 = dinv[r4.z], dr3 = dinv[r4.w];
        float dc0 = dinv[c4.x], dc1 = dinv[c4.y], dc2 = dinv[c4.z], dc3 = dinv[c4.w];
        int p0 = atomicAdd(&cursor[c4.x], 1);
        int p1 = atomicAdd(&cursor[c4.y], 1);
        int p2 = atomicAdd(&cursor[c4.z], 1);
        int p3 = atomicAdd(&cursor[c4.w], 1);
        int2 e0; e0.x = r4.x; e0.y = __float_as_int(dr0 * dc0);
        int2 e1; e1.x = r4.y; e1.y = __float_as_int(dr1 * dc1);
        int2 e2; e2.x = r4.z; e2.y = __float_as_int(dr2 * dc2);
        int2 e3; e3.x = r4.w; e3.y = __float_as_int(dr3 * dc3);
        csr[p0] = e0; csr[p1] = e1; csr[p2] = e2; csr[p3] = e3;
    } else {
        for (int e = base; e < E; ++e) {
            int r = row[e], c = col[e];
            int pos = atomicAdd(&cursor[c], 1);
            int2 p; p.x = r; p.y = __float_as_int(dinv[r] * dinv[c]);
            csr[pos] = p;
        }
    }
}

// ---------------------------------------------------------------------------
// Layer-1 GEMM: pre-split bf16 A planes (hi/lo), 3 MFMAs/tile -> bf16 out.
// Layouts: A[m=lane&15][k=quad*8+j]  B[k=quad*8+j][n=lane&15]  D[row=quad*4+r][col=lane&15]
__global__ __launch_bounds__(256) void gemm_mfma_splitA(const unsigned short* __restrict__ Ahi,
                                                        const unsigned short* __restrict__ Alo,
                                                        const unsigned short* __restrict__ WtHi,
                                                        const unsigned short* __restrict__ WtLo,
                                                        unsigned short* __restrict__ Yb, int N) {
    int lane = threadIdx.x & 63;
    int wv   = threadIdx.x >> 6;
    int m16  = lane & 15;
    int quad = lane >> 4;
    int nodeBase = blockIdx.x * 32;

    f32x4 acc[2][2] = {};

    #pragma unroll
    for (int kt = 0; kt < 4; ++kt) {
        int k0 = kt * 32 + quad * 8;

        ushort8 aHi[2], aLo[2];
        #pragma unroll
        for (int mi = 0; mi < 2; ++mi) {
            int node = nodeBase + mi * 16 + m16;
            if (node >= N) node = N - 1;
            size_t off = (size_t)node * H_DIM + k0;
            aHi[mi] = *(const ushort8*)(Ahi + off);
            aLo[mi] = *(const ushort8*)(Alo + off);
        }

        ushort8 bHi[2], bLo[2];
        #pragma unroll
        for (int ni = 0; ni < 2; ++ni) {
            int n = (wv * 2 + ni) * 16 + m16;
            size_t off = (size_t)n * H_DIM + k0;
            bHi[ni] = *(const ushort8*)(WtHi + off);
            bLo[ni] = *(const ushort8*)(WtLo + off);
        }

        #pragma unroll
        for (int mi = 0; mi < 2; ++mi)
            #pragma unroll
            for (int ni = 0; ni < 2; ++ni) {
                acc[mi][ni] = __builtin_amdgcn_mfma_f32_16x16x32_bf16(
                    __builtin_bit_cast(bf16x8, aHi[mi]),
                    __builtin_bit_cast(bf16x8, bHi[ni]), acc[mi][ni], 0, 0, 0);
                acc[mi][ni] = __builtin_amdgcn_mfma_f32_16x16x32_bf16(
                    __builtin_bit_cast(bf16x8, aLo[mi]),
                    __builtin_bit_cast(bf16x8, bHi[ni]), acc[mi][ni], 0, 0, 0);
                acc[mi][ni] = __builtin_amdgcn_mfma_f32_16x16x32_bf16(
                    __builtin_bit_cast(bf16x8, aHi[mi]),
                    __builtin_bit_cast(bf16x8, bLo[ni]), acc[mi][ni], 0, 0, 0);
            }
    }

    #pragma unroll
    for (int mi = 0; mi < 2; ++mi)
        #pragma unroll
        for (int r = 0; r < 4; ++r) {
            int node = nodeBase + mi * 16 + quad * 4 + r;
            if (node < N) {
                #pragma unroll
                for (int ni = 0; ni < 2; ++ni) {
                    int c = (wv * 2 + ni) * 16 + m16;
                    Yb[(size_t)node * H_DIM + c] = f2bf_rne(acc[mi][ni][r]);
                }
            }
        }
}

// ---------------------------------------------------------------------------
// Layer-2 GEMM: bf16 A (exact, 16B loads, 2 MFMAs) -> bf16 out.
__global__ __launch_bounds__(256) void gemm_mfma_bf16A(const unsigned short* __restrict__ Xb,
                                                       const unsigned short* __restrict__ WtHi,
                                                       const unsigned short* __restrict__ WtLo,
                                                       unsigned short* __restrict__ Yb, int N) {
    int lane = threadIdx.x & 63;
    int wv   = threadIdx.x >> 6;
    int m16  = lane & 15;
    int quad = lane >> 4;
    int nodeBase = blockIdx.x * 32;

    f32x4 acc[2][2] = {};

    #pragma unroll
    for (int kt = 0; kt < 4; ++kt) {
        int k0 = kt * 32 + quad * 8;

        ushort8 a[2];
        #pragma unroll
        for (int mi = 0; mi < 2; ++mi) {
            int node = nodeBase + mi * 16 + m16;
            if (node >= N) node = N - 1;
            a[mi] = *(const ushort8*)(Xb + (size_t)node * H_DIM + k0);
        }

        ushort8 bHi[2], bLo[2];
        #pragma unroll
        for (int ni = 0; ni < 2; ++ni) {
            int n = (wv * 2 + ni) * 16 + m16;
            size_t off = (size_t)n * H_DIM + k0;
            bHi[ni] = *(const ushort8*)(WtHi + off);
            bLo[ni] = *(const ushort8*)(WtLo + off);
        }

        #pragma unroll
        for (int mi = 0; mi < 2; ++mi)
            #pragma unroll
            for (int ni = 0; ni < 2; ++ni) {
                acc[mi][ni] = __builtin_amdgcn_mfma_f32_16x16x32_bf16(
                    __builtin_bit_cast(bf16x8, a[mi]),
                    __builtin_bit_cast(bf16x8, bHi[ni]), acc[mi][ni], 0, 0, 0);
                acc[mi][ni] = __builtin_amdgcn_mfma_f32_16x16x32_bf16(
                    __builtin_bit_cast(bf16x8, a[mi]),
                    __builtin_bit_cast(bf16x8, bLo[ni]), acc[mi][ni], 0, 0, 0);
            }
    }

    #pragma unroll
    for (int mi = 0; mi < 2; ++mi)
        #pragma unroll
        for (int r = 0; r < 4; ++r) {
            int node = nodeBase + mi * 16 + quad * 4 + r;
            if (node < N) {
                #pragma unroll
                for (int ni = 0; ni < 2; ++ni) {
                    int c = (wv * 2 + ni) * 16 + m16;
                    Yb[(size_t)node * H_DIM + c] = f2bf_rne(acc[mi][ni][r]);
                }
            }
        }
}

// ---------------------------------------------------------------------------
// One wave per destination node.  Cooperative csr staging (64 entries in one
// coalesced 8B/lane load) + 4-deep gather pipeline.  LOW VGPR (~12) is the
// point: 8 waves/SIMD resident beats deeper per-wave ILP (R8 post-mortem).
__global__ __launch_bounds__(256) void agg_fused(const unsigned short* __restrict__ XWb,
                                                 const float* __restrict__ dinv,
                                                 const int2* __restrict__ csr,
                                                 const int* __restrict__ offs,
                                                 const float* __restrict__ bias,
                                                 unsigned short* __restrict__ OUTb, int N) {
    int wave = (blockIdx.x * 256 + threadIdx.x) >> 6;
    int lane = threadIdx.x & 63;
    if (wave >= N) return;
    int c = wave;
    int start = offs[c], end = offs[c + 1];
    float dc = dinv[c];
    const unsigned int* XW32 = (const unsigned int*)XWb;

    float ax0, ay0;
    {   // self loop
        unsigned int u = XW32[(size_t)c * 64 + lane];
        float s = dc * dc;
        ax0 = bf_lo(u) * s; ay0 = bf_hi(u) * s;
    }
    float ax1 = 0.f, ay1 = 0.f, ax2 = 0.f, ay2 = 0.f, ax3 = 0.f, ay3 = 0.f;

    for (int base = start; base < end; base += 64) {
        int m = end - base; if (m > 64) m = 64;
        int2 ce; ce.x = 0; ce.y = 0;
        if (lane < m) ce = csr[base + lane];          // coalesced segment stage

        int j = 0;
        for (; j + 3 < m; j += 4) {
            int r0 = __shfl(ce.x, j);     int b0 = __shfl(ce.y, j);
            int r1 = __shfl(ce.x, j + 1); int b1 = __shfl(ce.y, j + 1);
            int r2 = __shfl(ce.x, j + 2); int b2 = __shfl(ce.y, j + 2);
            int r3 = __shfl(ce.x, j + 3); int b3 = __shfl(ce.y, j + 3);
            unsigned int g0 = XW32[(size_t)r0 * 64 + lane];
            unsigned int g1 = XW32[(size_t)r1 * 64 + lane];
            unsigned int g2 = XW32[(size_t)r2 * 64 + lane];
            unsigned int g3 = XW32[(size_t)r3 * 64 + lane];
            float n0 = __int_as_float(b0);
            float n1 = __int_as_float(b1);
            float n2 = __int_as_float(b2);
            float n3 = __int_as_float(b3);
            ax0 += bf_lo(g0) * n0; ay0 += bf_hi(g0) * n0;
            ax1 += bf_lo(g1) * n1; ay1 += bf_hi(g1) * n1;
            ax2 += bf_lo(g2) * n2; ay2 += bf_hi(g2) * n2;
            ax3 += bf_lo(g3) * n3; ay3 += bf_hi(g3) * n3;
        }
        for (; j < m; ++j) {
            int r = __shfl(ce.x, j); int b = __shfl(ce.y, j);
            unsigned int g = XW32[(size_t)r * 64 + lane];
            float nrm = __int_as_float(b);
            ax1 += bf_lo(g) * nrm; ay1 += bf_hi(g) * nrm;
        }
    }
    float ax = (ax0 + ax1) + (ax2 + ax3);
    float ay = (ay0 + ay1) + (ay2 + ay3);
    float2 b = ((const float2*)bias)[lane];
    ax = fmaxf(ax + b.x, 0.f);
    ay = fmaxf(ay + b.y, 0.f);
    unsigned int o = (unsigned int)f2bf_rne(ax) | ((unsigned int)f2bf_rne(ay) << 16);
    ((unsigned int*)(OUTb + (size_t)c * H_DIM))[lane] = o;
}

// ---------------------------------------------------------------------------
// Pooling phase 1: partial sums, atomics flushed per graph-boundary crossing.
__global__ __launch_bounds__(256) void pool_partial(const unsigned short* __restrict__ Hb,
                                                    const int* __restrict__ batch,
                                                    float* __restrict__ pooledSum, int N) {
    __shared__ int sb[64];
    int base = blockIdx.x * 64;
    int t = threadIdx.x;
    if (t < 64) {
        int idx = base + t;
        sb[t] = (idx < N) ? batch[idx] : -1;
    }
    __syncthreads();
    int f   = t & 127;
    int sub = t >> 7;            // 0..1
    int n0  = sub * 32;
    float acc = 0.f;
    int curg = -1;
    #pragma unroll 4
    for (int i = 0; i < 32; ++i) {
        int n = base + n0 + i;
        if (n >= N) break;
        int g = sb[n0 + i];
        if (g != curg) {
            if (curg >= 0) atomicAdd(&pooledSum[curg * H_DIM + f], acc);
            acc = 0.f; curg = g;
        }
        acc += __uint_as_float(((unsigned int)Hb[(size_t)n * H_DIM + f]) << 16);
    }
    if (curg >= 0) atomicAdd(&pooledSum[curg * H_DIM + f], acc);
}

// ---------------------------------------------------------------------------
// Head: count via binary search on sorted batch, mean, FC, log-softmax.
__global__ __launch_bounds__(64) void head_kernel(const float* __restrict__ pooledSum,
                                                  const int* __restrict__ batch,
                                                  const float* __restrict__ Wfc,
                                                  const float* __restrict__ bfc,
                                                  float* __restrict__ out, int N) {
    __shared__ float sl[OUT_DIM + 2];
    __shared__ int bounds[2];
    int g = blockIdx.x;
    int j = threadIdx.x;
    if (j < 2) {
        int v = g + j;
        int lo = 0, hi = N;
        while (lo < hi) {
            int mid = (lo + hi) >> 1;
            if (batch[mid] < v) lo = mid + 1; else hi = mid;
        }
        bounds[j] = lo;
    }
    __syncthreads();
    int cnt = bounds[1] - bounds[0];
    float inv = 1.0f / (float)(cnt > 0 ? cnt : 1);
    if (j < OUT_DIM) {
        float acc = 0.f;
        const float* p = pooledSum + g * H_DIM;
        for (int k = 0; k < H_DIM; ++k) acc += p[k] * Wfc[k * OUT_DIM + j];
        sl[j] = acc * inv + bfc[j];
    }
    __syncthreads();
    if (j == 0) {
        float m = sl[0];
        for (int i = 1; i < OUT_DIM; ++i) m = fmaxf(m, sl[i]);
        float s = 0.f;
        for (int i = 0; i < OUT_DIM; ++i) s += expf(sl[i] - m);
        sl[OUT_DIM] = m + logf(s);
    }
    __syncthreads();
    if (j < OUT_DIM) out[g * OUT_DIM + j] = sl[j] - sl[OUT_DIM];
}

// ---------------------------------------------------------------------------
extern "C" void kernel_launch(void* const* d_in, const int* in_sizes, int n_in,
                              void* d_out, int out_size, void* d_ws, size_t ws_size,
                              hipStream_t stream) {
    const float* x     = (const float*)d_in[0];
    const int*   ei    = (const int*)  d_in[1];
    const int*   batch = (const int*)  d_in[2];
    const float* W1    = (const float*)d_in[3];
    const float* b1    = (const float*)d_in[4];
    const float* W2    = (const float*)d_in[5];
    const float* b2    = (const float*)d_in[6];
    const float* Wfc   = (const float*)d_in[7];
    const float* bfc   = (const float*)d_in[8];
    float* out = (float*)d_out;

    int N = in_sizes[2];
    int E = in_sizes[1] / 2;
    int G = out_size / OUT_DIM;
    const int* row = ei;
    const int* col = ei + E;

    // Workspace layout (ONE memset zeroes cnt+pooledSum, adjacent):
    // cnt[nAlign] | pooledSum[G*128] | offs[nAlign] | cursor[nAlign] | dinv[nAlign]
    //   | csr[E] int2 | Xb[N*128] us | Hb[N*128] us
    //   | blockSums[256] | blockOffs[256] | Wt{1,2}{Hi,Lo}[16384] us
    //   | Xhi[N*128] us | Xlo[N*128] us
    char* wsb = (char*)d_ws;
    size_t nAlign = (size_t)((N + 256) / 256) * 256;   // >= N+1
    int*   cnt       = (int*)wsb;
    float* pooledSum = (float*)(cnt + nAlign);
    int*   offs      = (int*)(pooledSum + (size_t)G * H_DIM);
    int*   cursor    = offs + nAlign;
    float* dinv      = (float*)(cursor + nAlign);
    int2*  csr       = (int2*)(dinv + nAlign);
    unsigned short* Xb = (unsigned short*)(csr + E);
    unsigned short* Hb = Xb + (size_t)N * H_DIM;
    int* blockSums = (int*)(Hb + (size_t)N * H_DIM);
    int* blockOffs = blockSums + 256;
    unsigned short* Wt1Hi = (unsigned short*)(blockOffs + 256);
    unsigned short* Wt1Lo = Wt1Hi + H_DIM * H_DIM;
    unsigned short* Wt2Hi = Wt1Lo + H_DIM * H_DIM;
    unsigned short* Wt2Lo = Wt2Hi + H_DIM * H_DIM;
    unsigned short* Xhi = Wt2Lo + H_DIM * H_DIM;
    unsigned short* Xlo = Xhi + (size_t)N * H_DIM;

    int scanBlocks = (N + 1023) / 1024;   // 40 for N=40000 (<=256 supported)
    int total8 = N * H_DIM / 8;
    int xb = (total8 + 255) / 256;
    int histBlocks = (E + 255) / 256;
    int scatThreads = (E + 3) / 4;

    // ---- One memset for cnt + pooledSum (adjacent)
    hipMemsetAsync(cnt, 0, (nAlign + (size_t)G * H_DIM) * sizeof(int), stream);

    // ---- Fused W-split + X-split + edge histogram
    prep_kernel<<<128 + xb + histBlocks, 256, 0, stream>>>(
        W1, W2, Wt1Hi, Wt1Lo, Wt2Hi, Wt2Lo, x, Xhi, Xlo, total8, xb, col, cnt, E);

    // ---- 3-phase scan (offs/cursor/dinv) + scatter (4 edges/thread)
    scan_phase1<<<scanBlocks, 256, 0, stream>>>(cnt, blockSums, dinv, N);
    scan_phase2<<<1, 256, 0, stream>>>(blockSums, blockOffs, offs, scanBlocks, N);
    scan_phase3<<<scanBlocks, 256, 0, stream>>>(cnt, blockOffs, offs, cursor, N);
    scatter_kernel<<<(scatThreads + 255) / 256, 256, 0, stream>>>(row, col, dinv, cursor, csr, E);

    int aggBlocks  = (N + 3) / 4;     // 4 waves/block, 1 wave/node
    int gemmBlocks = (N + 31) / 32;   // 32 nodes/block

    // ---- Layer 1
    gemm_mfma_splitA<<<gemmBlocks, 256, 0, stream>>>(Xhi, Xlo, Wt1Hi, Wt1Lo, Xb, N);
    agg_fused<<<aggBlocks, 256, 0, stream>>>(Xb, dinv, csr, offs, b1, Hb, N);

    // ---- Layer 2 (reuse Xb for XW2)
    gemm_mfma_bf16A<<<gemmBlocks, 256, 0, stream>>>(Hb, Wt2Hi, Wt2Lo, Xb, N);
    agg_fused<<<aggBlocks, 256, 0, stream>>>(Xb, dinv, csr, offs, b2, Hb, N);

    // ---- Pool (partial sums + atomics) + head (count/divide folded in)
    pool_partial<<<(N + 63) / 64, 256, 0, stream>>>(Hb, batch, pooledSum, N);
    head_kernel<<<G, 64, 0, stream>>>(pooledSum, batch, Wfc, bfc, out, N);
}

// Round 13
// 257.938 us; speedup vs baseline: 1.0764x; 1.0764x over previous
//
#include <hip/hip_runtime.h>
#include <math.h>

#define H_DIM 128
#define OUT_DIM 10

typedef __attribute__((ext_vector_type(8))) __bf16 bf16x8;
typedef __attribute__((ext_vector_type(8))) unsigned short ushort8;
typedef __attribute__((ext_vector_type(4))) float f32x4;

__device__ inline unsigned short f2bf_rne(float f) {
    unsigned int u = __float_as_uint(f);
    unsigned int r = u + 0x7FFFu + ((u >> 16) & 1u);
    return (unsigned short)(r >> 16);
}
__device__ inline float bf_lo(unsigned int u) { return __uint_as_float(u << 16); }
__device__ inline float bf_hi(unsigned int u) { return __uint_as_float(u & 0xFFFF0000u); }

// ---------------------------------------------------------------------------
// Fused prep: [0,128) W1+W2 split/transpose; [128,128+xb) X split;
// [128+xb, ...) edge histogram; the atomic's RETURN VALUE is the edge's rank
// within its destination bucket -> stored so scatter needs no atomics.
__global__ __launch_bounds__(256) void prep_kernel(const float* __restrict__ W1,
                                                   const float* __restrict__ W2,
                                                   unsigned short* __restrict__ Wt1Hi,
                                                   unsigned short* __restrict__ Wt1Lo,
                                                   unsigned short* __restrict__ Wt2Hi,
                                                   unsigned short* __restrict__ Wt2Lo,
                                                   const float* __restrict__ X,
                                                   unsigned short* __restrict__ Xhi,
                                                   unsigned short* __restrict__ Xlo,
                                                   int total8, int xb,
                                                   const int* __restrict__ col,
                                                   int* __restrict__ cnt,
                                                   int* __restrict__ rank, int E) {
    if (blockIdx.x < 128) {
        int i = blockIdx.x * 256 + threadIdx.x;   // 0..32767
        const float* src   = (i < 16384) ? W1    : W2;
        unsigned short* dh = (i < 16384) ? Wt1Hi : Wt2Hi;
        unsigned short* dl = (i < 16384) ? Wt1Lo : Wt2Lo;
        int idx = i & 16383;
        int k = idx >> 7, n = idx & 127;
        float v = src[idx];                        // W[k][n]
        unsigned short hb = f2bf_rne(v);
        float hf = __uint_as_float((unsigned int)hb << 16);
        unsigned short lb = f2bf_rne(v - hf);
        dh[n * H_DIM + k] = hb;
        dl[n * H_DIM + k] = lb;
    } else if (blockIdx.x < 128 + xb) {
        int i = (blockIdx.x - 128) * 256 + threadIdx.x;
        if (i >= total8) return;
        const float* p = X + (size_t)i * 8;
        f32x4 a = *(const f32x4*)p;
        f32x4 b = *(const f32x4*)(p + 4);
        float v[8] = {a.x, a.y, a.z, a.w, b.x, b.y, b.z, b.w};
        ushort8 h, l;
        #pragma unroll
        for (int j = 0; j < 8; ++j) {
            unsigned short hb = f2bf_rne(v[j]);
            float hf = __uint_as_float((unsigned int)hb << 16);
            h[j] = hb;
            l[j] = f2bf_rne(v[j] - hf);
        }
        *(ushort8*)(Xhi + (size_t)i * 8) = h;
        *(ushort8*)(Xlo + (size_t)i * 8) = l;
    } else {
        int e = (blockIdx.x - 128 - xb) * 256 + threadIdx.x;
        if (e < E) rank[e] = atomicAdd(&cnt[col[e]], 1);
    }
}

// ---------------------------------------------------------------------------
// Hierarchical 3-phase scan (proven; single-pass lookback regressed — cross-
// XCD atomic spin chains are an anti-pattern).  Phase1 also computes dinv.
__global__ __launch_bounds__(256) void scan_phase1(const int* __restrict__ cnt,
                                                   int* __restrict__ blockSums,
                                                   float* __restrict__ dinv, int N) {
    __shared__ int red[256];
    int base = blockIdx.x * 1024;
    int t = threadIdx.x;
    int s = 0;
    for (int i = 0; i < 4; ++i) {
        int idx = base + t * 4 + i;
        if (idx < N) {
            int cv = cnt[idx];
            s += cv;
            dinv[idx] = rsqrtf((float)cv + 1.0f);   // deg>=1 (self loop)
        }
    }
    red[t] = s;
    __syncthreads();
    for (int d = 128; d > 0; d >>= 1) {
        if (t < d) red[t] += red[t + d];
        __syncthreads();
    }
    if (t == 0) blockSums[blockIdx.x] = red[0];
}

__global__ __launch_bounds__(256) void scan_phase2(const int* __restrict__ blockSums,
                                                   int* __restrict__ blockOffs,
                                                   int* __restrict__ offs, int B, int N) {
    __shared__ int sh[256];
    int t = threadIdx.x;
    sh[t] = (t < B) ? blockSums[t] : 0;
    __syncthreads();
    for (int d = 1; d < 256; d <<= 1) {
        int v = (t >= d) ? sh[t - d] : 0;
        __syncthreads();
        sh[t] += v;
        __syncthreads();
    }
    if (t < B) blockOffs[t] = (t == 0) ? 0 : sh[t - 1];
    if (t == 255) offs[N] = sh[255];   // == E
}

__global__ __launch_bounds__(256) void scan_phase3(const int* __restrict__ cnt,
                                                   const int* __restrict__ blockOffs,
                                                   int* __restrict__ offs, int N) {
    __shared__ int red[256];
    int base = blockIdx.x * 1024;
    int t = threadIdx.x;
    int v[4];
    int s = 0;
    for (int i = 0; i < 4; ++i) {
        int idx = base + t * 4 + i;
        v[i] = (idx < N) ? cnt[idx] : 0;
        s += v[i];
    }
    red[t] = s;
    __syncthreads();
    for (int d = 1; d < 256; d <<= 1) {   // inclusive Hillis-Steele
        int x = (t >= d) ? red[t - d] : 0;
        __syncthreads();
        red[t] += x;
        __syncthreads();
    }
    int run = blockOffs[blockIdx.x] + ((t == 0) ? 0 : red[t - 1]);
    for (int i = 0; i < 4; ++i) {
        int idx = base + t * 4 + i;
        if (idx < N) { offs[idx] = run; run += v[i]; }
    }
}

// ---------------------------------------------------------------------------
// Atomic-free scatter: pos = offs[col[e]] + rank[e] (rank captured in prep).
// Pure streaming loads + one fire-and-forget random 8B store per edge.
__global__ __launch_bounds__(256) void scatter_kernel(const int* __restrict__ row,
                                                      const int* __restrict__ col,
                                                      const int* __restrict__ rank,
                                                      const float* __restrict__ dinv,
                                                      const int* __restrict__ offs,
                                                      int2* __restrict__ csr, int E) {
    int e = blockIdx.x * 256 + threadIdx.x;
    if (e >= E) return;
    int r = row[e], c = col[e], rk = rank[e];
    int pos = offs[c] + rk;
    int2 p; p.x = r; p.y = __float_as_int(dinv[r] * dinv[c]);
    csr[pos] = p;
}

// ---------------------------------------------------------------------------
// Layer-1 GEMM: pre-split bf16 A planes (hi/lo), 3 MFMAs/tile -> bf16 out.
// Layouts: A[m=lane&15][k=quad*8+j]  B[k=quad*8+j][n=lane&15]  D[row=quad*4+r][col=lane&15]
__global__ __launch_bounds__(256) void gemm_mfma_splitA(const unsigned short* __restrict__ Ahi,
                                                        const unsigned short* __restrict__ Alo,
                                                        const unsigned short* __restrict__ WtHi,
                                                        const unsigned short* __restrict__ WtLo,
                                                        unsigned short* __restrict__ Yb, int N) {
    int lane = threadIdx.x & 63;
    int wv   = threadIdx.x >> 6;
    int m16  = lane & 15;
    int quad = lane >> 4;
    int nodeBase = blockIdx.x * 32;

    f32x4 acc[2][2] = {};

    #pragma unroll
    for (int kt = 0; kt < 4; ++kt) {
        int k0 = kt * 32 + quad * 8;

        ushort8 aHi[2], aLo[2];
        #pragma unroll
        for (int mi = 0; mi < 2; ++mi) {
            int node = nodeBase + mi * 16 + m16;
            if (node >= N) node = N - 1;
            size_t off = (size_t)node * H_DIM + k0;
            aHi[mi] = *(const ushort8*)(Ahi + off);
            aLo[mi] = *(const ushort8*)(Alo + off);
        }

        ushort8 bHi[2], bLo[2];
        #pragma unroll
        for (int ni = 0; ni < 2; ++ni) {
            int n = (wv * 2 + ni) * 16 + m16;
            size_t off = (size_t)n * H_DIM + k0;
            bHi[ni] = *(const ushort8*)(WtHi + off);
            bLo[ni] = *(const ushort8*)(WtLo + off);
        }

        #pragma unroll
        for (int mi = 0; mi < 2; ++mi)
            #pragma unroll
            for (int ni = 0; ni < 2; ++ni) {
                acc[mi][ni] = __builtin_amdgcn_mfma_f32_16x16x32_bf16(
                    __builtin_bit_cast(bf16x8, aHi[mi]),
                    __builtin_bit_cast(bf16x8, bHi[ni]), acc[mi][ni], 0, 0, 0);
                acc[mi][ni] = __builtin_amdgcn_mfma_f32_16x16x32_bf16(
                    __builtin_bit_cast(bf16x8, aLo[mi]),
                    __builtin_bit_cast(bf16x8, bHi[ni]), acc[mi][ni], 0, 0, 0);
                acc[mi][ni] = __builtin_amdgcn_mfma_f32_16x16x32_bf16(
                    __builtin_bit_cast(bf16x8, aHi[mi]),
                    __builtin_bit_cast(bf16x8, bLo[ni]), acc[mi][ni], 0, 0, 0);
            }
    }

    #pragma unroll
    for (int mi = 0; mi < 2; ++mi)
        #pragma unroll
        for (int r = 0; r < 4; ++r) {
            int node = nodeBase + mi * 16 + quad * 4 + r;
            if (node < N) {
                #pragma unroll
                for (int ni = 0; ni < 2; ++ni) {
                    int c = (wv * 2 + ni) * 16 + m16;
                    Yb[(size_t)node * H_DIM + c] = f2bf_rne(acc[mi][ni][r]);
                }
            }
        }
}

// ---------------------------------------------------------------------------
// Layer-2 GEMM: bf16 A (exact, 16B loads, 2 MFMAs) -> bf16 out.
__global__ __launch_bounds__(256) void gemm_mfma_bf16A(const unsigned short* __restrict__ Xb,
                                                       const unsigned short* __restrict__ WtHi,
                                                       const unsigned short* __restrict__ WtLo,
                                                       unsigned short* __restrict__ Yb, int N) {
    int lane = threadIdx.x & 63;
    int wv   = threadIdx.x >> 6;
    int m16  = lane & 15;
    int quad = lane >> 4;
    int nodeBase = blockIdx.x * 32;

    f32x4 acc[2][2] = {};

    #pragma unroll
    for (int kt = 0; kt < 4; ++kt) {
        int k0 = kt * 32 + quad * 8;

        ushort8 a[2];
        #pragma unroll
        for (int mi = 0; mi < 2; ++mi) {
            int node = nodeBase + mi * 16 + m16;
            if (node >= N) node = N - 1;
            a[mi] = *(const ushort8*)(Xb + (size_t)node * H_DIM + k0);
        }

        ushort8 bHi[2], bLo[2];
        #pragma unroll
        for (int ni = 0; ni < 2; ++ni) {
            int n = (wv * 2 + ni) * 16 + m16;
            size_t off = (size_t)n * H_DIM + k0;
            bHi[ni] = *(const ushort8*)(WtHi + off);
            bLo[ni] = *(const ushort8*)(WtLo + off);
        }

        #pragma unroll
        for (int mi = 0; mi < 2; ++mi)
            #pragma unroll
            for (int ni = 0; ni < 2; ++ni) {
                acc[mi][ni] = __builtin_amdgcn_mfma_f32_16x16x32_bf16(
                    __builtin_bit_cast(bf16x8, a[mi]),
                    __builtin_bit_cast(bf16x8, bHi[ni]), acc[mi][ni], 0, 0, 0);
                acc[mi][ni] = __builtin_amdgcn_mfma_f32_16x16x32_bf16(
                    __builtin_bit_cast(bf16x8, a[mi]),
                    __builtin_bit_cast(bf16x8, bLo[ni]), acc[mi][ni], 0, 0, 0);
            }
    }

    #pragma unroll
    for (int mi = 0; mi < 2; ++mi)
        #pragma unroll
        for (int r = 0; r < 4; ++r) {
            int node = nodeBase + mi * 16 + quad * 4 + r;
            if (node < N) {
                #pragma unroll
                for (int ni = 0; ni < 2; ++ni) {
                    int c = (wv * 2 + ni) * 16 + m16;
                    Yb[(size_t)node * H_DIM + c] = f2bf_rne(acc[mi][ni][r]);
                }
            }
        }
}

// ---------------------------------------------------------------------------
// One wave per destination node.  Cooperative csr staging (64 entries in one
// coalesced 8B/lane load) + 4-deep gather pipeline.  LOW VGPR (~12) is the
// point: 8 waves/SIMD resident beats deeper per-wave ILP (R8 post-mortem).
__global__ __launch_bounds__(256) void agg_fused(const unsigned short* __restrict__ XWb,
                                                 const float* __restrict__ dinv,
                                                 const int2* __restrict__ csr,
                                                 const int* __restrict__ offs,
                                                 const float* __restrict__ bias,
                                                 unsigned short* __restrict__ OUTb, int N) {
    int wave = (blockIdx.x * 256 + threadIdx.x) >> 6;
    int lane = threadIdx.x & 63;
    if (wave >= N) return;
    int c = wave;
    int start = offs[c], end = offs[c + 1];
    float dc = dinv[c];
    const unsigned int* XW32 = (const unsigned int*)XWb;

    float ax0, ay0;
    {   // self loop
        unsigned int u = XW32[(size_t)c * 64 + lane];
        float s = dc * dc;
        ax0 = bf_lo(u) * s; ay0 = bf_hi(u) * s;
    }
    float ax1 = 0.f, ay1 = 0.f, ax2 = 0.f, ay2 = 0.f, ax3 = 0.f, ay3 = 0.f;

    for (int base = start; base < end; base += 64) {
        int m = end - base; if (m > 64) m = 64;
        int2 ce; ce.x = 0; ce.y = 0;
        if (lane < m) ce = csr[base + lane];          // coalesced segment stage

        int j = 0;
        for (; j + 3 < m; j += 4) {
            int r0 = __shfl(ce.x, j);     int b0 = __shfl(ce.y, j);
            int r1 = __shfl(ce.x, j + 1); int b1 = __shfl(ce.y, j + 1);
            int r2 = __shfl(ce.x, j + 2); int b2 = __shfl(ce.y, j + 2);
            int r3 = __shfl(ce.x, j + 3); int b3 = __shfl(ce.y, j + 3);
            unsigned int g0 = XW32[(size_t)r0 * 64 + lane];
            unsigned int g1 = XW32[(size_t)r1 * 64 + lane];
            unsigned int g2 = XW32[(size_t)r2 * 64 + lane];
            unsigned int g3 = XW32[(size_t)r3 * 64 + lane];
            float n0 = __int_as_float(b0);
            float n1 = __int_as_float(b1);
            float n2 = __int_as_float(b2);
            float n3 = __int_as_float(b3);
            ax0 += bf_lo(g0) * n0; ay0 += bf_hi(g0) * n0;
            ax1 += bf_lo(g1) * n1; ay1 += bf_hi(g1) * n1;
            ax2 += bf_lo(g2) * n2; ay2 += bf_hi(g2) * n2;
            ax3 += bf_lo(g3) * n3; ay3 += bf_hi(g3) * n3;
        }
        for (; j < m; ++j) {
            int r = __shfl(ce.x, j); int b = __shfl(ce.y, j);
            unsigned int g = XW32[(size_t)r * 64 + lane];
            float nrm = __int_as_float(b);
            ax1 += bf_lo(g) * nrm; ay1 += bf_hi(g) * nrm;
        }
    }
    float ax = (ax0 + ax1) + (ax2 + ax3);
    float ay = (ay0 + ay1) + (ay2 + ay3);
    float2 b = ((const float2*)bias)[lane];
    ax = fmaxf(ax + b.x, 0.f);
    ay = fmaxf(ay + b.y, 0.f);
    unsigned int o = (unsigned int)f2bf_rne(ax) | ((unsigned int)f2bf_rne(ay) << 16);
    ((unsigned int*)(OUTb + (size_t)c * H_DIM))[lane] = o;
}

// ---------------------------------------------------------------------------
// Pooling phase 1: partial sums, atomics flushed per graph-boundary crossing.
__global__ __launch_bounds__(256) void pool_partial(const unsigned short* __restrict__ Hb,
                                                    const int* __restrict__ batch,
                                                    float* __restrict__ pooledSum, int N) {
    __shared__ int sb[64];
    int base = blockIdx.x * 64;
    int t = threadIdx.x;
    if (t < 64) {
        int idx = base + t;
        sb[t] = (idx < N) ? batch[idx] : -1;
    }
    __syncthreads();
    int f   = t & 127;
    int sub = t >> 7;            // 0..1
    int n0  = sub * 32;
    float acc = 0.f;
    int curg = -1;
    #pragma unroll 4
    for (int i = 0; i < 32; ++i) {
        int n = base + n0 + i;
        if (n >= N) break;
        int g = sb[n0 + i];
        if (g != curg) {
            if (curg >= 0) atomicAdd(&pooledSum[curg * H_DIM + f], acc);
            acc = 0.f; curg = g;
        }
        acc += __uint_as_float(((unsigned int)Hb[(size_t)n * H_DIM + f]) << 16);
    }
    if (curg >= 0) atomicAdd(&pooledSum[curg * H_DIM + f], acc);
}

// ---------------------------------------------------------------------------
// Head: count via binary search on sorted batch, mean, FC, log-softmax.
__global__ __launch_bounds__(64) void head_kernel(const float* __restrict__ pooledSum,
                                                  const int* __restrict__ batch,
                                                  const float* __restrict__ Wfc,
                                                  const float* __restrict__ bfc,
                                                  float* __restrict__ out, int N) {
    __shared__ float sl[OUT_DIM + 2];
    __shared__ int bounds[2];
    int g = blockIdx.x;
    int j = threadIdx.x;
    if (j < 2) {
        int v = g + j;
        int lo = 0, hi = N;
        while (lo < hi) {
            int mid = (lo + hi) >> 1;
            if (batch[mid] < v) lo = mid + 1; else hi = mid;
        }
        bounds[j] = lo;
    }
    __syncthreads();
    int cnt = bounds[1] - bounds[0];
    float inv = 1.0f / (float)(cnt > 0 ? cnt : 1);
    if (j < OUT_DIM) {
        float acc = 0.f;
        const float* p = pooledSum + g * H_DIM;
        for (int k = 0; k < H_DIM; ++k) acc += p[k] * Wfc[k * OUT_DIM + j];
        sl[j] = acc * inv + bfc[j];
    }
    __syncthreads();
    if (j == 0) {
        float m = sl[0];
        for (int i = 1; i < OUT_DIM; ++i) m = fmaxf(m, sl[i]);
        float s = 0.f;
        for (int i = 0; i < OUT_DIM; ++i) s += expf(sl[i] - m);
        sl[OUT_DIM] = m + logf(s);
    }
    __syncthreads();
    if (j < OUT_DIM) out[g * OUT_DIM + j] = sl[j] - sl[OUT_DIM];
}

// ---------------------------------------------------------------------------
extern "C" void kernel_launch(void* const* d_in, const int* in_sizes, int n_in,
                              void* d_out, int out_size, void* d_ws, size_t ws_size,
                              hipStream_t stream) {
    const float* x     = (const float*)d_in[0];
    const int*   ei    = (const int*)  d_in[1];
    const int*   batch = (const int*)  d_in[2];
    const float* W1    = (const float*)d_in[3];
    const float* b1    = (const float*)d_in[4];
    const float* W2    = (const float*)d_in[5];
    const float* b2    = (const float*)d_in[6];
    const float* Wfc   = (const float*)d_in[7];
    const float* bfc   = (const float*)d_in[8];
    float* out = (float*)d_out;

    int N = in_sizes[2];
    int E = in_sizes[1] / 2;
    int G = out_size / OUT_DIM;
    const int* row = ei;
    const int* col = ei + E;

    // Workspace layout (ONE memset zeroes cnt+pooledSum, adjacent):
    // cnt[nAlign] | pooledSum[G*128] | offs[nAlign] | rank[E] | dinv[nAlign]
    //   | csr[E] int2 | Xb[N*128] us | Hb[N*128] us
    //   | blockSums[256] | blockOffs[256] | Wt{1,2}{Hi,Lo}[16384] us
    //   | Xhi[N*128] us | Xlo[N*128] us
    char* wsb = (char*)d_ws;
    size_t nAlign = (size_t)((N + 256) / 256) * 256;   // >= N+1
    size_t eAlign = (size_t)((E + 255) / 256) * 256;
    int*   cnt       = (int*)wsb;
    float* pooledSum = (float*)(cnt + nAlign);
    int*   offs      = (int*)(pooledSum + (size_t)G * H_DIM);
    int*   rank      = offs + nAlign;
    float* dinv      = (float*)(rank + eAlign);
    int2*  csr       = (int2*)(dinv + nAlign);
    unsigned short* Xb = (unsigned short*)(csr + E);
    unsigned short* Hb = Xb + (size_t)N * H_DIM;
    int* blockSums = (int*)(Hb + (size_t)N * H_DIM);
    int* blockOffs = blockSums + 256;
    unsigned short* Wt1Hi = (unsigned short*)(blockOffs + 256);
    unsigned short* Wt1Lo = Wt1Hi + H_DIM * H_DIM;
    unsigned short* Wt2Hi = Wt1Lo + H_DIM * H_DIM;
    unsigned short* Wt2Lo = Wt2Hi + H_DIM * H_DIM;
    unsigned short* Xhi = Wt2Lo + H_DIM * H_DIM;
    unsigned short* Xlo = Xhi + (size_t)N * H_DIM;

    int scanBlocks = (N + 1023) / 1024;   // 40 for N=40000 (<=256 supported)
    int total8 = N * H_DIM / 8;
    int xb = (total8 + 255) / 256;
    int histBlocks = (E + 255) / 256;

    // ---- One memset for cnt + pooledSum (adjacent)
    hipMemsetAsync(cnt, 0, (nAlign + (size_t)G * H_DIM) * sizeof(int), stream);

    // ---- Fused W-split + X-split + edge histogram (rank capture)
    prep_kernel<<<128 + xb + histBlocks, 256, 0, stream>>>(
        W1, W2, Wt1Hi, Wt1Lo, Wt2Hi, Wt2Lo, x, Xhi, Xlo, total8, xb, col, cnt, rank, E);

    // ---- 3-phase scan (offs/dinv) + atomic-free scatter
    scan_phase1<<<scanBlocks, 256, 0, stream>>>(cnt, blockSums, dinv, N);
    scan_phase2<<<1, 256, 0, stream>>>(blockSums, blockOffs, offs, scanBlocks, N);
    scan_phase3<<<scanBlocks, 256, 0, stream>>>(cnt, blockOffs, offs, N);
    scatter_kernel<<<(E + 255) / 256, 256, 0, stream>>>(row, col, rank, dinv, offs, csr, E);

    int aggBlocks  = (N + 3) / 4;     // 4 waves/block, 1 wave/node
    int gemmBlocks = (N + 31) / 32;   // 32 nodes/block

    // ---- Layer 1
    gemm_mfma_splitA<<<gemmBlocks, 256, 0, stream>>>(Xhi, Xlo, Wt1Hi, Wt1Lo, Xb, N);
    agg_fused<<<aggBlocks, 256, 0, stream>>>(Xb, dinv, csr, offs, b1, Hb, N);

    // ---- Layer 2 (reuse Xb for XW2)
    gemm_mfma_bf16A<<<gemmBlocks, 256, 0, stream>>>(Hb, Wt2Hi, Wt2Lo, Xb, N);
    agg_fused<<<aggBlocks, 256, 0, stream>>>(Xb, dinv, csr, offs, b2, Hb, N);

    // ---- Pool (partial sums + atomics) + head (count/divide folded in)
    pool_partial<<<(N + 63) / 64, 256, 0, stream>>>(Hb, batch, pooledSum, N);
    head_kernel<<<G, 64, 0, stream>>>(pooledSum, batch, Wfc, bfc, out, N);
}

// Round 14
// 249.876 us; speedup vs baseline: 1.1111x; 1.0323x over previous
//
#include <hip/hip_runtime.h>
#include <math.h>

#define H_DIM 128
#define OUT_DIM 10

typedef __attribute__((ext_vector_type(8))) __bf16 bf16x8;
typedef __attribute__((ext_vector_type(8))) unsigned short ushort8;
typedef __attribute__((ext_vector_type(4))) float f32x4;

__device__ inline unsigned short f2bf_rne(float f) {
    unsigned int u = __float_as_uint(f);
    unsigned int r = u + 0x7FFFu + ((u >> 16) & 1u);
    return (unsigned short)(r >> 16);
}
__device__ inline float bf_lo(unsigned int u) { return __uint_as_float(u << 16); }
__device__ inline float bf_hi(unsigned int u) { return __uint_as_float(u & 0xFFFF0000u); }

// ---------------------------------------------------------------------------
// Fused prep.  Branch ORDER matters (R14): histogram FIRST so its atomic-
// return stalls overlap with the streaming W/X-split blocks dispatched after;
// with hist last (R13) the grid tail was pure atomic-latency stall (52-57us).
// [0,hb): edge histogram + rank capture; [hb,hb+128): W split/transpose;
// [hb+128,...): X split.  cnt zeroed by preceding memset.
__global__ __launch_bounds__(256) void prep_kernel(const float* __restrict__ W1,
                                                   const float* __restrict__ W2,
                                                   unsigned short* __restrict__ Wt1Hi,
                                                   unsigned short* __restrict__ Wt1Lo,
                                                   unsigned short* __restrict__ Wt2Hi,
                                                   unsigned short* __restrict__ Wt2Lo,
                                                   const float* __restrict__ X,
                                                   unsigned short* __restrict__ Xhi,
                                                   unsigned short* __restrict__ Xlo,
                                                   int total8, int hb,
                                                   const int* __restrict__ col,
                                                   int* __restrict__ cnt,
                                                   int* __restrict__ rank, int E) {
    if (blockIdx.x < hb) {
        int e = blockIdx.x * 256 + threadIdx.x;
        if (e < E) rank[e] = atomicAdd(&cnt[col[e]], 1);
    } else if (blockIdx.x < hb + 128) {
        int i = (blockIdx.x - hb) * 256 + threadIdx.x;   // 0..32767
        const float* src   = (i < 16384) ? W1    : W2;
        unsigned short* dh = (i < 16384) ? Wt1Hi : Wt2Hi;
        unsigned short* dl = (i < 16384) ? Wt1Lo : Wt2Lo;
        int idx = i & 16383;
        int k = idx >> 7, n = idx & 127;
        float v = src[idx];                        // W[k][n]
        unsigned short hbv = f2bf_rne(v);
        float hf = __uint_as_float((unsigned int)hbv << 16);
        unsigned short lb = f2bf_rne(v - hf);
        dh[n * H_DIM + k] = hbv;
        dl[n * H_DIM + k] = lb;
    } else {
        int i = (blockIdx.x - hb - 128) * 256 + threadIdx.x;
        if (i >= total8) return;
        const float* p = X + (size_t)i * 8;
        f32x4 a = *(const f32x4*)p;
        f32x4 b = *(const f32x4*)(p + 4);
        float v[8] = {a.x, a.y, a.z, a.w, b.x, b.y, b.z, b.w};
        ushort8 h, l;
        #pragma unroll
        for (int j = 0; j < 8; ++j) {
            unsigned short hbv = f2bf_rne(v[j]);
            float hf = __uint_as_float((unsigned int)hbv << 16);
            h[j] = hbv;
            l[j] = f2bf_rne(v[j] - hf);
        }
        *(ushort8*)(Xhi + (size_t)i * 8) = h;
        *(ushort8*)(Xlo + (size_t)i * 8) = l;
    }
}

// ---------------------------------------------------------------------------
// Hierarchical 3-phase scan (proven; single-pass lookback regressed — cross-
// XCD atomic spin chains are an anti-pattern).  Phase1 also computes dinv.
__global__ __launch_bounds__(256) void scan_phase1(const int* __restrict__ cnt,
                                                   int* __restrict__ blockSums,
                                                   float* __restrict__ dinv, int N) {
    __shared__ int red[256];
    int base = blockIdx.x * 1024;
    int t = threadIdx.x;
    int s = 0;
    for (int i = 0; i < 4; ++i) {
        int idx = base + t * 4 + i;
        if (idx < N) {
            int cv = cnt[idx];
            s += cv;
            dinv[idx] = rsqrtf((float)cv + 1.0f);   // deg>=1 (self loop)
        }
    }
    red[t] = s;
    __syncthreads();
    for (int d = 128; d > 0; d >>= 1) {
        if (t < d) red[t] += red[t + d];
        __syncthreads();
    }
    if (t == 0) blockSums[blockIdx.x] = red[0];
}

__global__ __launch_bounds__(256) void scan_phase2(const int* __restrict__ blockSums,
                                                   int* __restrict__ blockOffs,
                                                   int* __restrict__ offs, int B, int N) {
    __shared__ int sh[256];
    int t = threadIdx.x;
    sh[t] = (t < B) ? blockSums[t] : 0;
    __syncthreads();
    for (int d = 1; d < 256; d <<= 1) {
        int v = (t >= d) ? sh[t - d] : 0;
        __syncthreads();
        sh[t] += v;
        __syncthreads();
    }
    if (t < B) blockOffs[t] = (t == 0) ? 0 : sh[t - 1];
    if (t == 255) offs[N] = sh[255];   // == E
}

__global__ __launch_bounds__(256) void scan_phase3(const int* __restrict__ cnt,
                                                   const int* __restrict__ blockOffs,
                                                   int* __restrict__ offs, int N) {
    __shared__ int red[256];
    int base = blockIdx.x * 1024;
    int t = threadIdx.x;
    int v[4];
    int s = 0;
    for (int i = 0; i < 4; ++i) {
        int idx = base + t * 4 + i;
        v[i] = (idx < N) ? cnt[idx] : 0;
        s += v[i];
    }
    red[t] = s;
    __syncthreads();
    for (int d = 1; d < 256; d <<= 1) {   // inclusive Hillis-Steele
        int x = (t >= d) ? red[t - d] : 0;
        __syncthreads();
        red[t] += x;
        __syncthreads();
    }
    int run = blockOffs[blockIdx.x] + ((t == 0) ? 0 : red[t - 1]);
    for (int i = 0; i < 4; ++i) {
        int idx = base + t * 4 + i;
        if (idx < N) { offs[idx] = run; run += v[i]; }
    }
}

// ---------------------------------------------------------------------------
// Atomic-free scatter: pos = offs[col[e]] + rank[e] (rank captured in prep).
// Pure streaming loads + one fire-and-forget random 8B store per edge.
__global__ __launch_bounds__(256) void scatter_kernel(const int* __restrict__ row,
                                                      const int* __restrict__ col,
                                                      const int* __restrict__ rank,
                                                      const float* __restrict__ dinv,
                                                      const int* __restrict__ offs,
                                                      int2* __restrict__ csr, int E) {
    int e = blockIdx.x * 256 + threadIdx.x;
    if (e >= E) return;
    int r = row[e], c = col[e], rk = rank[e];
    int pos = offs[c] + rk;
    int2 p; p.x = r; p.y = __float_as_int(dinv[r] * dinv[c]);
    csr[pos] = p;
}

// ---------------------------------------------------------------------------
// Layer-1 GEMM: pre-split bf16 A planes (hi/lo), 3 MFMAs/tile -> bf16 out.
// Layouts: A[m=lane&15][k=quad*8+j]  B[k=quad*8+j][n=lane&15]  D[row=quad*4+r][col=lane&15]
__global__ __launch_bounds__(256) void gemm_mfma_splitA(const unsigned short* __restrict__ Ahi,
                                                        const unsigned short* __restrict__ Alo,
                                                        const unsigned short* __restrict__ WtHi,
                                                        const unsigned short* __restrict__ WtLo,
                                                        unsigned short* __restrict__ Yb, int N) {
    int lane = threadIdx.x & 63;
    int wv   = threadIdx.x >> 6;
    int m16  = lane & 15;
    int quad = lane >> 4;
    int nodeBase = blockIdx.x * 32;

    f32x4 acc[2][2] = {};

    #pragma unroll
    for (int kt = 0; kt < 4; ++kt) {
        int k0 = kt * 32 + quad * 8;

        ushort8 aHi[2], aLo[2];
        #pragma unroll
        for (int mi = 0; mi < 2; ++mi) {
            int node = nodeBase + mi * 16 + m16;
            if (node >= N) node = N - 1;
            size_t off = (size_t)node * H_DIM + k0;
            aHi[mi] = *(const ushort8*)(Ahi + off);
            aLo[mi] = *(const ushort8*)(Alo + off);
        }

        ushort8 bHi[2], bLo[2];
        #pragma unroll
        for (int ni = 0; ni < 2; ++ni) {
            int n = (wv * 2 + ni) * 16 + m16;
            size_t off = (size_t)n * H_DIM + k0;
            bHi[ni] = *(const ushort8*)(WtHi + off);
            bLo[ni] = *(const ushort8*)(WtLo + off);
        }

        #pragma unroll
        for (int mi = 0; mi < 2; ++mi)
            #pragma unroll
            for (int ni = 0; ni < 2; ++ni) {
                acc[mi][ni] = __builtin_amdgcn_mfma_f32_16x16x32_bf16(
                    __builtin_bit_cast(bf16x8, aHi[mi]),
                    __builtin_bit_cast(bf16x8, bHi[ni]), acc[mi][ni], 0, 0, 0);
                acc[mi][ni] = __builtin_amdgcn_mfma_f32_16x16x32_bf16(
                    __builtin_bit_cast(bf16x8, aLo[mi]),
                    __builtin_bit_cast(bf16x8, bHi[ni]), acc[mi][ni], 0, 0, 0);
                acc[mi][ni] = __builtin_amdgcn_mfma_f32_16x16x32_bf16(
                    __builtin_bit_cast(bf16x8, aHi[mi]),
                    __builtin_bit_cast(bf16x8, bLo[ni]), acc[mi][ni], 0, 0, 0);
            }
    }

    #pragma unroll
    for (int mi = 0; mi < 2; ++mi)
        #pragma unroll
        for (int r = 0; r < 4; ++r) {
            int node = nodeBase + mi * 16 + quad * 4 + r;
            if (node < N) {
                #pragma unroll
                for (int ni = 0; ni < 2; ++ni) {
                    int c = (wv * 2 + ni) * 16 + m16;
                    Yb[(size_t)node * H_DIM + c] = f2bf_rne(acc[mi][ni][r]);
                }
            }
        }
}

// ---------------------------------------------------------------------------
// Layer-2 GEMM: bf16 A (exact, 16B loads, 2 MFMAs) -> bf16 out.
__global__ __launch_bounds__(256) void gemm_mfma_bf16A(const unsigned short* __restrict__ Xb,
                                                       const unsigned short* __restrict__ WtHi,
                                                       const unsigned short* __restrict__ WtLo,
                                                       unsigned short* __restrict__ Yb, int N) {
    int lane = threadIdx.x & 63;
    int wv   = threadIdx.x >> 6;
    int m16  = lane & 15;
    int quad = lane >> 4;
    int nodeBase = blockIdx.x * 32;

    f32x4 acc[2][2] = {};

    #pragma unroll
    for (int kt = 0; kt < 4; ++kt) {
        int k0 = kt * 32 + quad * 8;

        ushort8 a[2];
        #pragma unroll
        for (int mi = 0; mi < 2; ++mi) {
            int node = nodeBase + mi * 16 + m16;
            if (node >= N) node = N - 1;
            a[mi] = *(const ushort8*)(Xb + (size_t)node * H_DIM + k0);
        }

        ushort8 bHi[2], bLo[2];
        #pragma unroll
        for (int ni = 0; ni < 2; ++ni) {
            int n = (wv * 2 + ni) * 16 + m16;
            size_t off = (size_t)n * H_DIM + k0;
            bHi[ni] = *(const ushort8*)(WtHi + off);
            bLo[ni] = *(const ushort8*)(WtLo + off);
        }

        #pragma unroll
        for (int mi = 0; mi < 2; ++mi)
            #pragma unroll
            for (int ni = 0; ni < 2; ++ni) {
                acc[mi][ni] = __builtin_amdgcn_mfma_f32_16x16x32_bf16(
                    __builtin_bit_cast(bf16x8, a[mi]),
                    __builtin_bit_cast(bf16x8, bHi[ni]), acc[mi][ni], 0, 0, 0);
                acc[mi][ni] = __builtin_amdgcn_mfma_f32_16x16x32_bf16(
                    __builtin_bit_cast(bf16x8, a[mi]),
                    __builtin_bit_cast(bf16x8, bLo[ni]), acc[mi][ni], 0, 0, 0);
            }
    }

    #pragma unroll
    for (int mi = 0; mi < 2; ++mi)
        #pragma unroll
        for (int r = 0; r < 4; ++r) {
            int node = nodeBase + mi * 16 + quad * 4 + r;
            if (node < N) {
                #pragma unroll
                for (int ni = 0; ni < 2; ++ni) {
                    int c = (wv * 2 + ni) * 16 + m16;
                    Yb[(size_t)node * H_DIM + c] = f2bf_rne(acc[mi][ni][r]);
                }
            }
        }
}

// ---------------------------------------------------------------------------
// One wave per destination node.  Cooperative csr staging (64 entries in one
// coalesced 8B/lane load) + 4-deep gather pipeline.  LOW VGPR (~12) is the
// point: 8 waves/SIMD resident beats deeper per-wave ILP (R8 post-mortem).
__global__ __launch_bounds__(256) void agg_fused(const unsigned short* __restrict__ XWb,
                                                 const float* __restrict__ dinv,
                                                 const int2* __restrict__ csr,
                                                 const int* __restrict__ offs,
                                                 const float* __restrict__ bias,
                                                 unsigned short* __restrict__ OUTb, int N) {
    int wave = (blockIdx.x * 256 + threadIdx.x) >> 6;
    int lane = threadIdx.x & 63;
    if (wave >= N) return;
    int c = wave;
    int start = offs[c], end = offs[c + 1];
    float dc = dinv[c];
    const unsigned int* XW32 = (const unsigned int*)XWb;

    float ax0, ay0;
    {   // self loop
        unsigned int u = XW32[(size_t)c * 64 + lane];
        float s = dc * dc;
        ax0 = bf_lo(u) * s; ay0 = bf_hi(u) * s;
    }
    float ax1 = 0.f, ay1 = 0.f, ax2 = 0.f, ay2 = 0.f, ax3 = 0.f, ay3 = 0.f;

    for (int base = start; base < end; base += 64) {
        int m = end - base; if (m > 64) m = 64;
        int2 ce; ce.x = 0; ce.y = 0;
        if (lane < m) ce = csr[base + lane];          // coalesced segment stage

        int j = 0;
        for (; j + 3 < m; j += 4) {
            int r0 = __shfl(ce.x, j);     int b0 = __shfl(ce.y, j);
            int r1 = __shfl(ce.x, j + 1); int b1 = __shfl(ce.y, j + 1);
            int r2 = __shfl(ce.x, j + 2); int b2 = __shfl(ce.y, j + 2);
            int r3 = __shfl(ce.x, j + 3); int b3 = __shfl(ce.y, j + 3);
            unsigned int g0 = XW32[(size_t)r0 * 64 + lane];
            unsigned int g1 = XW32[(size_t)r1 * 64 + lane];
            unsigned int g2 = XW32[(size_t)r2 * 64 + lane];
            unsigned int g3 = XW32[(size_t)r3 * 64 + lane];
            float n0 = __int_as_float(b0);
            float n1 = __int_as_float(b1);
            float n2 = __int_as_float(b2);
            float n3 = __int_as_float(b3);
            ax0 += bf_lo(g0) * n0; ay0 += bf_hi(g0) * n0;
            ax1 += bf_lo(g1) * n1; ay1 += bf_hi(g1) * n1;
            ax2 += bf_lo(g2) * n2; ay2 += bf_hi(g2) * n2;
            ax3 += bf_lo(g3) * n3; ay3 += bf_hi(g3) * n3;
        }
        for (; j < m; ++j) {
            int r = __shfl(ce.x, j); int b = __shfl(ce.y, j);
            unsigned int g = XW32[(size_t)r * 64 + lane];
            float nrm = __int_as_float(b);
            ax1 += bf_lo(g) * nrm; ay1 += bf_hi(g) * nrm;
        }
    }
    float ax = (ax0 + ax1) + (ax2 + ax3);
    float ay = (ay0 + ay1) + (ay2 + ay3);
    float2 b = ((const float2*)bias)[lane];
    ax = fmaxf(ax + b.x, 0.f);
    ay = fmaxf(ay + b.y, 0.f);
    unsigned int o = (unsigned int)f2bf_rne(ax) | ((unsigned int)f2bf_rne(ay) << 16);
    ((unsigned int*)(OUTb + (size_t)c * H_DIM))[lane] = o;
}

// ---------------------------------------------------------------------------
// Pooling phase 1: partial sums, atomics flushed per graph-boundary crossing.
__global__ __launch_bounds__(256) void pool_partial(const unsigned short* __restrict__ Hb,
                                                    const int* __restrict__ batch,
                                                    float* __restrict__ pooledSum, int N) {
    __shared__ int sb[64];
    int base = blockIdx.x * 64;
    int t = threadIdx.x;
    if (t < 64) {
        int idx = base + t;
        sb[t] = (idx < N) ? batch[idx] : -1;
    }
    __syncthreads();
    int f   = t & 127;
    int sub = t >> 7;            // 0..1
    int n0  = sub * 32;
    float acc = 0.f;
    int curg = -1;
    #pragma unroll 4
    for (int i = 0; i < 32; ++i) {
        int n = base + n0 + i;
        if (n >= N) break;
        int g = sb[n0 + i];
        if (g != curg) {
            if (curg >= 0) atomicAdd(&pooledSum[curg * H_DIM + f], acc);
            acc = 0.f; curg = g;
        }
        acc += __uint_as_float(((unsigned int)Hb[(size_t)n * H_DIM + f]) << 16);
    }
    if (curg >= 0) atomicAdd(&pooledSum[curg * H_DIM + f], acc);
}

// ---------------------------------------------------------------------------
// Head: count via binary search on sorted batch, mean, FC, log-softmax.
__global__ __launch_bounds__(64) void head_kernel(const float* __restrict__ pooledSum,
                                                  const int* __restrict__ batch,
                                                  const float* __restrict__ Wfc,
                                                  const float* __restrict__ bfc,
                                                  float* __restrict__ out, int N) {
    __shared__ float sl[OUT_DIM + 2];
    __shared__ int bounds[2];
    int g = blockIdx.x;
    int j = threadIdx.x;
    if (j < 2) {
        int v = g + j;
        int lo = 0, hi = N;
        while (lo < hi) {
            int mid = (lo + hi) >> 1;
            if (batch[mid] < v) lo = mid + 1; else hi = mid;
        }
        bounds[j] = lo;
    }
    __syncthreads();
    int cnt = bounds[1] - bounds[0];
    float inv = 1.0f / (float)(cnt > 0 ? cnt : 1);
    if (j < OUT_DIM) {
        float acc = 0.f;
        const float* p = pooledSum + g * H_DIM;
        for (int k = 0; k < H_DIM; ++k) acc += p[k] * Wfc[k * OUT_DIM + j];
        sl[j] = acc * inv + bfc[j];
    }
    __syncthreads();
    if (j == 0) {
        float m = sl[0];
        for (int i = 1; i < OUT_DIM; ++i) m = fmaxf(m, sl[i]);
        float s = 0.f;
        for (int i = 0; i < OUT_DIM; ++i) s += expf(sl[i] - m);
        sl[OUT_DIM] = m + logf(s);
    }
    __syncthreads();
    if (j < OUT_DIM) out[g * OUT_DIM + j] = sl[j] - sl[OUT_DIM];
}

// ---------------------------------------------------------------------------
extern "C" void kernel_launch(void* const* d_in, const int* in_sizes, int n_in,
                              void* d_out, int out_size, void* d_ws, size_t ws_size,
                              hipStream_t stream) {
    const float* x     = (const float*)d_in[0];
    const int*   ei    = (const int*)  d_in[1];
    const int*   batch = (const int*)  d_in[2];
    const float* W1    = (const float*)d_in[3];
    const float* b1    = (const float*)d_in[4];
    const float* W2    = (const float*)d_in[5];
    const float* b2    = (const float*)d_in[6];
    const float* Wfc   = (const float*)d_in[7];
    const float* bfc   = (const float*)d_in[8];
    float* out = (float*)d_out;

    int N = in_sizes[2];
    int E = in_sizes[1] / 2;
    int G = out_size / OUT_DIM;
    const int* row = ei;
    const int* col = ei + E;

    // Workspace layout (ONE memset zeroes cnt+pooledSum, adjacent):
    // cnt[nAlign] | pooledSum[G*128] | offs[nAlign] | rank[E] | dinv[nAlign]
    //   | csr[E] int2 | Xb[N*128] us | Hb[N*128] us
    //   | blockSums[256] | blockOffs[256] | Wt{1,2}{Hi,Lo}[16384] us
    //   | Xhi[N*128] us | Xlo[N*128] us
    char* wsb = (char*)d_ws;
    size_t nAlign = (size_t)((N + 256) / 256) * 256;   // >= N+1
    size_t eAlign = (size_t)((E + 255) / 256) * 256;
    int*   cnt       = (int*)wsb;
    float* pooledSum = (float*)(cnt + nAlign);
    int*   offs      = (int*)(pooledSum + (size_t)G * H_DIM);
    int*   rank      = offs + nAlign;
    float* dinv      = (float*)(rank + eAlign);
    int2*  csr       = (int2*)(dinv + nAlign);
    unsigned short* Xb = (unsigned short*)(csr + E);
    unsigned short* Hb = Xb + (size_t)N * H_DIM;
    int* blockSums = (int*)(Hb + (size_t)N * H_DIM);
    int* blockOffs = blockSums + 256;
    unsigned short* Wt1Hi = (unsigned short*)(blockOffs + 256);
    unsigned short* Wt1Lo = Wt1Hi + H_DIM * H_DIM;
    unsigned short* Wt2Hi = Wt1Lo + H_DIM * H_DIM;
    unsigned short* Wt2Lo = Wt2Hi + H_DIM * H_DIM;
    unsigned short* Xhi = Wt2Lo + H_DIM * H_DIM;
    unsigned short* Xlo = Xhi + (size_t)N * H_DIM;

    int scanBlocks = (N + 1023) / 1024;   // 40 for N=40000 (<=256 supported)
    int total8 = N * H_DIM / 8;
    int xb = (total8 + 255) / 256;
    int histBlocks = (E + 255) / 256;

    // ---- One memset for cnt + pooledSum (adjacent)
    hipMemsetAsync(cnt, 0, (nAlign + (size_t)G * H_DIM) * sizeof(int), stream);

    // ---- Fused histogram (FIRST — latency overlaps following streaming
    //      branches) + W-split + X-split
    prep_kernel<<<histBlocks + 128 + xb, 256, 0, stream>>>(
        W1, W2, Wt1Hi, Wt1Lo, Wt2Hi, Wt2Lo, x, Xhi, Xlo, total8, histBlocks,
        col, cnt, rank, E);

    // ---- 3-phase scan (offs/dinv) + atomic-free scatter
    scan_phase1<<<scanBlocks, 256, 0, stream>>>(cnt, blockSums, dinv, N);
    scan_phase2<<<1, 256, 0, stream>>>(blockSums, blockOffs, offs, scanBlocks, N);
    scan_phase3<<<scanBlocks, 256, 0, stream>>>(cnt, blockOffs, offs, N);
    scatter_kernel<<<(E + 255) / 256, 256, 0, stream>>>(row, col, rank, dinv, offs, csr, E);

    int aggBlocks  = (N + 3) / 4;     // 4 waves/block, 1 wave/node
    int gemmBlocks = (N + 31) / 32;   // 32 nodes/block

    // ---- Layer 1
    gemm_mfma_splitA<<<gemmBlocks, 256, 0, stream>>>(Xhi, Xlo, Wt1Hi, Wt1Lo, Xb, N);
    agg_fused<<<aggBlocks, 256, 0, stream>>>(Xb, dinv, csr, offs, b1, Hb, N);

    // ---- Layer 2 (reuse Xb for XW2)
    gemm_mfma_bf16A<<<gemmBlocks, 256, 0, stream>>>(Hb, Wt2Hi, Wt2Lo, Xb, N);
    agg_fused<<<aggBlocks, 256, 0, stream>>>(Xb, dinv, csr, offs, b2, Hb, N);

    // ---- Pool (partial sums + atomics) + head (count/divide folded in)
    pool_partial<<<(N + 63) / 64, 256, 0, stream>>>(Hb, batch, pooledSum, N);
    head_kernel<<<G, 64, 0, stream>>>(pooledSum, batch, Wfc, bfc, out, N);
}

// Round 15
// 245.602 us; speedup vs baseline: 1.1304x; 1.0174x over previous
//
#include <hip/hip_runtime.h>
#include <math.h>

#define H_DIM 128
#define OUT_DIM 10

typedef __attribute__((ext_vector_type(8))) __bf16 bf16x8;
typedef __attribute__((ext_vector_type(8))) unsigned short ushort8;
typedef __attribute__((ext_vector_type(4))) float f32x4;

__device__ inline unsigned short f2bf_rne(float f) {
    unsigned int u = __float_as_uint(f);
    unsigned int r = u + 0x7FFFu + ((u >> 16) & 1u);
    return (unsigned short)(r >> 16);
}
__device__ inline float bf_lo(unsigned int u) { return __uint_as_float(u << 16); }
__device__ inline float bf_hi(unsigned int u) { return __uint_as_float(u & 0xFFFF0000u); }

// ---------------------------------------------------------------------------
// Fused prep.  Histogram FIRST (R14: its atomic-return stalls overlap with
// the streaming W/X-split blocks dispatched after).
__global__ __launch_bounds__(256) void prep_kernel(const float* __restrict__ W1,
                                                   const float* __restrict__ W2,
                                                   unsigned short* __restrict__ Wt1Hi,
                                                   unsigned short* __restrict__ Wt1Lo,
                                                   unsigned short* __restrict__ Wt2Hi,
                                                   unsigned short* __restrict__ Wt2Lo,
                                                   const float* __restrict__ X,
                                                   unsigned short* __restrict__ Xhi,
                                                   unsigned short* __restrict__ Xlo,
                                                   int total8, int hb,
                                                   const int* __restrict__ col,
                                                   int* __restrict__ cnt,
                                                   int* __restrict__ rank, int E) {
    if (blockIdx.x < hb) {
        int e = blockIdx.x * 256 + threadIdx.x;
        if (e < E) rank[e] = atomicAdd(&cnt[col[e]], 1);
    } else if (blockIdx.x < hb + 128) {
        int i = (blockIdx.x - hb) * 256 + threadIdx.x;   // 0..32767
        const float* src   = (i < 16384) ? W1    : W2;
        unsigned short* dh = (i < 16384) ? Wt1Hi : Wt2Hi;
        unsigned short* dl = (i < 16384) ? Wt1Lo : Wt2Lo;
        int idx = i & 16383;
        int k = idx >> 7, n = idx & 127;
        float v = src[idx];                        // W[k][n]
        unsigned short hbv = f2bf_rne(v);
        float hf = __uint_as_float((unsigned int)hbv << 16);
        unsigned short lb = f2bf_rne(v - hf);
        dh[n * H_DIM + k] = hbv;
        dl[n * H_DIM + k] = lb;
    } else {
        int i = (blockIdx.x - hb - 128) * 256 + threadIdx.x;
        if (i >= total8) return;
        const float* p = X + (size_t)i * 8;
        f32x4 a = *(const f32x4*)p;
        f32x4 b = *(const f32x4*)(p + 4);
        float v[8] = {a.x, a.y, a.z, a.w, b.x, b.y, b.z, b.w};
        ushort8 h, l;
        #pragma unroll
        for (int j = 0; j < 8; ++j) {
            unsigned short hbv = f2bf_rne(v[j]);
            float hf = __uint_as_float((unsigned int)hbv << 16);
            h[j] = hbv;
            l[j] = f2bf_rne(v[j] - hf);
        }
        *(ushort8*)(Xhi + (size_t)i * 8) = h;
        *(ushort8*)(Xlo + (size_t)i * 8) = l;
    }
}

// ---------------------------------------------------------------------------
// Scan phase1: per-block reduce of cnt + dinv computation.
__global__ __launch_bounds__(256) void scan_phase1(const int* __restrict__ cnt,
                                                   int* __restrict__ blockSums,
                                                   float* __restrict__ dinv, int N) {
    __shared__ int red[256];
    int base = blockIdx.x * 1024;
    int t = threadIdx.x;
    int s = 0;
    for (int i = 0; i < 4; ++i) {
        int idx = base + t * 4 + i;
        if (idx < N) {
            int cv = cnt[idx];
            s += cv;
            dinv[idx] = rsqrtf((float)cv + 1.0f);   // deg>=1 (self loop)
        }
    }
    red[t] = s;
    __syncthreads();
    for (int d = 128; d > 0; d >>= 1) {
        if (t < d) red[t] += red[t + d];
        __syncthreads();
    }
    if (t == 0) blockSums[blockIdx.x] = red[0];
}

// ---------------------------------------------------------------------------
// Scan phase2+3 fused: each block redundantly reduces blockSums[0..bid) for
// its own offset (B<=256, trivial), then does the local inclusive scan and
// writes offs.  Last block writes offs[N]=E.
__global__ __launch_bounds__(256) void scan_phase23(const int* __restrict__ cnt,
                                                    const int* __restrict__ blockSums,
                                                    int* __restrict__ offs, int N, int B) {
    __shared__ int red[256];
    __shared__ int bsum[256];
    int base = blockIdx.x * 1024;
    int t = threadIdx.x;

    bsum[t] = (t < B && t < (int)blockIdx.x) ? blockSums[t] : 0;

    int v[4];
    int s = 0;
    for (int i = 0; i < 4; ++i) {
        int idx = base + t * 4 + i;
        v[i] = (idx < N) ? cnt[idx] : 0;
        s += v[i];
    }
    red[t] = s;
    __syncthreads();
    // tree-reduce bsum -> bsum[0] (this block's global offset)
    for (int d = 128; d > 0; d >>= 1) {
        if (t < d) bsum[t] += bsum[t + d];
        __syncthreads();
    }
    for (int d = 1; d < 256; d <<= 1) {   // inclusive Hillis-Steele on red
        int x = (t >= d) ? red[t - d] : 0;
        __syncthreads();
        red[t] += x;
        __syncthreads();
    }
    int run = bsum[0] + ((t == 0) ? 0 : red[t - 1]);
    for (int i = 0; i < 4; ++i) {
        int idx = base + t * 4 + i;
        if (idx < N) { offs[idx] = run; run += v[i]; }
    }
    if ((int)blockIdx.x == B - 1 && t == 255) offs[N] = run;   // == E
}

// ---------------------------------------------------------------------------
// FUSED scatter + layer-1 GEMM.  The two are independent (scatter needs
// rank/offs/dinv; gemm needs Xhi/Xlo/Wt) — fusing lets scatter's random-store
// latency hide under the GEMM's MFMA waves on the same CUs (R14 lesson,
// applied at dispatch level).  Scatter blocks FIRST.
__global__ __launch_bounds__(256) void scatter_gemm1(
        const int* __restrict__ row, const int* __restrict__ col,
        const int* __restrict__ rank, const float* __restrict__ dinv,
        const int* __restrict__ offs, int2* __restrict__ csr, int E, int sb,
        const unsigned short* __restrict__ Ahi, const unsigned short* __restrict__ Alo,
        const unsigned short* __restrict__ WtHi, const unsigned short* __restrict__ WtLo,
        unsigned short* __restrict__ Yb, int N) {
    if (blockIdx.x < (unsigned)sb) {
        // ---- scatter branch: pos = offs[col] + rank, fire-and-forget store
        int e = blockIdx.x * 256 + threadIdx.x;
        if (e >= E) return;
        int r = row[e], c = col[e], rk = rank[e];
        int pos = offs[c] + rk;
        int2 p; p.x = r; p.y = __float_as_int(dinv[r] * dinv[c]);
        csr[pos] = p;
        return;
    }
    // ---- gemm branch (identical to gemm_mfma_splitA)
    int blk  = blockIdx.x - sb;
    int lane = threadIdx.x & 63;
    int wv   = threadIdx.x >> 6;
    int m16  = lane & 15;
    int quad = lane >> 4;
    int nodeBase = blk * 32;

    f32x4 acc[2][2] = {};

    #pragma unroll
    for (int kt = 0; kt < 4; ++kt) {
        int k0 = kt * 32 + quad * 8;

        ushort8 aHi[2], aLo[2];
        #pragma unroll
        for (int mi = 0; mi < 2; ++mi) {
            int node = nodeBase + mi * 16 + m16;
            if (node >= N) node = N - 1;
            size_t off = (size_t)node * H_DIM + k0;
            aHi[mi] = *(const ushort8*)(Ahi + off);
            aLo[mi] = *(const ushort8*)(Alo + off);
        }

        ushort8 bHi[2], bLo[2];
        #pragma unroll
        for (int ni = 0; ni < 2; ++ni) {
            int n = (wv * 2 + ni) * 16 + m16;
            size_t off = (size_t)n * H_DIM + k0;
            bHi[ni] = *(const ushort8*)(WtHi + off);
            bLo[ni] = *(const ushort8*)(WtLo + off);
        }

        #pragma unroll
        for (int mi = 0; mi < 2; ++mi)
            #pragma unroll
            for (int ni = 0; ni < 2; ++ni) {
                acc[mi][ni] = __builtin_amdgcn_mfma_f32_16x16x32_bf16(
                    __builtin_bit_cast(bf16x8, aHi[mi]),
                    __builtin_bit_cast(bf16x8, bHi[ni]), acc[mi][ni], 0, 0, 0);
                acc[mi][ni] = __builtin_amdgcn_mfma_f32_16x16x32_bf16(
                    __builtin_bit_cast(bf16x8, aLo[mi]),
                    __builtin_bit_cast(bf16x8, bHi[ni]), acc[mi][ni], 0, 0, 0);
                acc[mi][ni] = __builtin_amdgcn_mfma_f32_16x16x32_bf16(
                    __builtin_bit_cast(bf16x8, aHi[mi]),
                    __builtin_bit_cast(bf16x8, bLo[ni]), acc[mi][ni], 0, 0, 0);
            }
    }

    #pragma unroll
    for (int mi = 0; mi < 2; ++mi)
        #pragma unroll
        for (int r = 0; r < 4; ++r) {
            int node = nodeBase + mi * 16 + quad * 4 + r;
            if (node < N) {
                #pragma unroll
                for (int ni = 0; ni < 2; ++ni) {
                    int c = (wv * 2 + ni) * 16 + m16;
                    Yb[(size_t)node * H_DIM + c] = f2bf_rne(acc[mi][ni][r]);
                }
            }
        }
}

// ---------------------------------------------------------------------------
// Layer-2 GEMM: bf16 A (exact, 16B loads, 2 MFMAs) -> bf16 out.
__global__ __launch_bounds__(256) void gemm_mfma_bf16A(const unsigned short* __restrict__ Xb,
                                                       const unsigned short* __restrict__ WtHi,
                                                       const unsigned short* __restrict__ WtLo,
                                                       unsigned short* __restrict__ Yb, int N) {
    int lane = threadIdx.x & 63;
    int wv   = threadIdx.x >> 6;
    int m16  = lane & 15;
    int quad = lane >> 4;
    int nodeBase = blockIdx.x * 32;

    f32x4 acc[2][2] = {};

    #pragma unroll
    for (int kt = 0; kt < 4; ++kt) {
        int k0 = kt * 32 + quad * 8;

        ushort8 a[2];
        #pragma unroll
        for (int mi = 0; mi < 2; ++mi) {
            int node = nodeBase + mi * 16 + m16;
            if (node >= N) node = N - 1;
            a[mi] = *(const ushort8*)(Xb + (size_t)node * H_DIM + k0);
        }

        ushort8 bHi[2], bLo[2];
        #pragma unroll
        for (int ni = 0; ni < 2; ++ni) {
            int n = (wv * 2 + ni) * 16 + m16;
            size_t off = (size_t)n * H_DIM + k0;
            bHi[ni] = *(const ushort8*)(WtHi + off);
            bLo[ni] = *(const ushort8*)(WtLo + off);
        }

        #pragma unroll
        for (int mi = 0; mi < 2; ++mi)
            #pragma unroll
            for (int ni = 0; ni < 2; ++ni) {
                acc[mi][ni] = __builtin_amdgcn_mfma_f32_16x16x32_bf16(
                    __builtin_bit_cast(bf16x8, a[mi]),
                    __builtin_bit_cast(bf16x8, bHi[ni]), acc[mi][ni], 0, 0, 0);
                acc[mi][ni] = __builtin_amdgcn_mfma_f32_16x16x32_bf16(
                    __builtin_bit_cast(bf16x8, a[mi]),
                    __builtin_bit_cast(bf16x8, bLo[ni]), acc[mi][ni], 0, 0, 0);
            }
    }

    #pragma unroll
    for (int mi = 0; mi < 2; ++mi)
        #pragma unroll
        for (int r = 0; r < 4; ++r) {
            int node = nodeBase + mi * 16 + quad * 4 + r;
            if (node < N) {
                #pragma unroll
                for (int ni = 0; ni < 2; ++ni) {
                    int c = (wv * 2 + ni) * 16 + m16;
                    Yb[(size_t)node * H_DIM + c] = f2bf_rne(acc[mi][ni][r]);
                }
            }
        }
}

// ---------------------------------------------------------------------------
// One wave per destination node.  Cooperative csr staging (64 entries in one
// coalesced 8B/lane load) + 4-deep gather pipeline.  LOW VGPR (~12) is the
// point: 8 waves/SIMD resident beats deeper per-wave ILP (R8 post-mortem).
__global__ __launch_bounds__(256) void agg_fused(const unsigned short* __restrict__ XWb,
                                                 const float* __restrict__ dinv,
                                                 const int2* __restrict__ csr,
                                                 const int* __restrict__ offs,
                                                 const float* __restrict__ bias,
                                                 unsigned short* __restrict__ OUTb, int N) {
    int wave = (blockIdx.x * 256 + threadIdx.x) >> 6;
    int lane = threadIdx.x & 63;
    if (wave >= N) return;
    int c = wave;
    int start = offs[c], end = offs[c + 1];
    float dc = dinv[c];
    const unsigned int* XW32 = (const unsigned int*)XWb;

    float ax0, ay0;
    {   // self loop
        unsigned int u = XW32[(size_t)c * 64 + lane];
        float s = dc * dc;
        ax0 = bf_lo(u) * s; ay0 = bf_hi(u) * s;
    }
    float ax1 = 0.f, ay1 = 0.f, ax2 = 0.f, ay2 = 0.f, ax3 = 0.f, ay3 = 0.f;

    for (int base = start; base < end; base += 64) {
        int m = end - base; if (m > 64) m = 64;
        int2 ce; ce.x = 0; ce.y = 0;
        if (lane < m) ce = csr[base + lane];          // coalesced segment stage

        int j = 0;
        for (; j + 3 < m; j += 4) {
            int r0 = __shfl(ce.x, j);     int b0 = __shfl(ce.y, j);
            int r1 = __shfl(ce.x, j + 1); int b1 = __shfl(ce.y, j + 1);
            int r2 = __shfl(ce.x, j + 2); int b2 = __shfl(ce.y, j + 2);
            int r3 = __shfl(ce.x, j + 3); int b3 = __shfl(ce.y, j + 3);
            unsigned int g0 = XW32[(size_t)r0 * 64 + lane];
            unsigned int g1 = XW32[(size_t)r1 * 64 + lane];
            unsigned int g2 = XW32[(size_t)r2 * 64 + lane];
            unsigned int g3 = XW32[(size_t)r3 * 64 + lane];
            float n0 = __int_as_float(b0);
            float n1 = __int_as_float(b1);
            float n2 = __int_as_float(b2);
            float n3 = __int_as_float(b3);
            ax0 += bf_lo(g0) * n0; ay0 += bf_hi(g0) * n0;
            ax1 += bf_lo(g1) * n1; ay1 += bf_hi(g1) * n1;
            ax2 += bf_lo(g2) * n2; ay2 += bf_hi(g2) * n2;
            ax3 += bf_lo(g3) * n3; ay3 += bf_hi(g3) * n3;
        }
        for (; j < m; ++j) {
            int r = __shfl(ce.x, j); int b = __shfl(ce.y, j);
            unsigned int g = XW32[(size_t)r * 64 + lane];
            float nrm = __int_as_float(b);
            ax1 += bf_lo(g) * nrm; ay1 += bf_hi(g) * nrm;
        }
    }
    float ax = (ax0 + ax1) + (ax2 + ax3);
    float ay = (ay0 + ay1) + (ay2 + ay3);
    float2 b = ((const float2*)bias)[lane];
    ax = fmaxf(ax + b.x, 0.f);
    ay = fmaxf(ay + b.y, 0.f);
    unsigned int o = (unsigned int)f2bf_rne(ax) | ((unsigned int)f2bf_rne(ay) << 16);
    ((unsigned int*)(OUTb + (size_t)c * H_DIM))[lane] = o;
}

// ---------------------------------------------------------------------------
// Pooling phase 1: partial sums, atomics flushed per graph-boundary crossing.
__global__ __launch_bounds__(256) void pool_partial(const unsigned short* __restrict__ Hb,
                                                    const int* __restrict__ batch,
                                                    float* __restrict__ pooledSum, int N) {
    __shared__ int sb[64];
    int base = blockIdx.x * 64;
    int t = threadIdx.x;
    if (t < 64) {
        int idx = base + t;
        sb[t] = (idx < N) ? batch[idx] : -1;
    }
    __syncthreads();
    int f   = t & 127;
    int sub = t >> 7;            // 0..1
    int n0  = sub * 32;
    float acc = 0.f;
    int curg = -1;
    #pragma unroll 4
    for (int i = 0; i < 32; ++i) {
        int n = base + n0 + i;
        if (n >= N) break;
        int g = sb[n0 + i];
        if (g != curg) {
            if (curg >= 0) atomicAdd(&pooledSum[curg * H_DIM + f], acc);
            acc = 0.f; curg = g;
        }
        acc += __uint_as_float(((unsigned int)Hb[(size_t)n * H_DIM + f]) << 16);
    }
    if (curg >= 0) atomicAdd(&pooledSum[curg * H_DIM + f], acc);
}

// ---------------------------------------------------------------------------
// Head: count via binary search on sorted batch, mean, FC, log-softmax.
__global__ __launch_bounds__(64) void head_kernel(const float* __restrict__ pooledSum,
                                                  const int* __restrict__ batch,
                                                  const float* __restrict__ Wfc,
                                                  const float* __restrict__ bfc,
                                                  float* __restrict__ out, int N) {
    __shared__ float sl[OUT_DIM + 2];
    __shared__ int bounds[2];
    int g = blockIdx.x;
    int j = threadIdx.x;
    if (j < 2) {
        int v = g + j;
        int lo = 0, hi = N;
        while (lo < hi) {
            int mid = (lo + hi) >> 1;
            if (batch[mid] < v) lo = mid + 1; else hi = mid;
        }
        bounds[j] = lo;
    }
    __syncthreads();
    int cnt = bounds[1] - bounds[0];
    float inv = 1.0f / (float)(cnt > 0 ? cnt : 1);
    if (j < OUT_DIM) {
        float acc = 0.f;
        const float* p = pooledSum + g * H_DIM;
        for (int k = 0; k < H_DIM; ++k) acc += p[k] * Wfc[k * OUT_DIM + j];
        sl[j] = acc * inv + bfc[j];
    }
    __syncthreads();
    if (j == 0) {
        float m = sl[0];
        for (int i = 1; i < OUT_DIM; ++i) m = fmaxf(m, sl[i]);
        float s = 0.f;
        for (int i = 0; i < OUT_DIM; ++i) s += expf(sl[i] - m);
        sl[OUT_DIM] = m + logf(s);
    }
    __syncthreads();
    if (j < OUT_DIM) out[g * OUT_DIM + j] = sl[j] - sl[OUT_DIM];
}

// ---------------------------------------------------------------------------
extern "C" void kernel_launch(void* const* d_in, const int* in_sizes, int n_in,
                              void* d_out, int out_size, void* d_ws, size_t ws_size,
                              hipStream_t stream) {
    const float* x     = (const float*)d_in[0];
    const int*   ei    = (const int*)  d_in[1];
    const int*   batch = (const int*)  d_in[2];
    const float* W1    = (const float*)d_in[3];
    const float* b1    = (const float*)d_in[4];
    const float* W2    = (const float*)d_in[5];
    const float* b2    = (const float*)d_in[6];
    const float* Wfc   = (const float*)d_in[7];
    const float* bfc   = (const float*)d_in[8];
    float* out = (float*)d_out;

    int N = in_sizes[2];
    int E = in_sizes[1] / 2;
    int G = out_size / OUT_DIM;
    const int* row = ei;
    const int* col = ei + E;

    // Workspace layout (ONE memset zeroes cnt+pooledSum, adjacent):
    // cnt[nAlign] | pooledSum[G*128] | offs[nAlign] | rank[E] | dinv[nAlign]
    //   | csr[E] int2 | Xb[N*128] us | Hb[N*128] us
    //   | blockSums[256] | Wt{1,2}{Hi,Lo}[16384] us | Xhi[N*128] us | Xlo[N*128] us
    char* wsb = (char*)d_ws;
    size_t nAlign = (size_t)((N + 256) / 256) * 256;   // >= N+1
    size_t eAlign = (size_t)((E + 255) / 256) * 256;
    int*   cnt       = (int*)wsb;
    float* pooledSum = (float*)(cnt + nAlign);
    int*   offs      = (int*)(pooledSum + (size_t)G * H_DIM);
    int*   rank      = offs + nAlign;
    float* dinv      = (float*)(rank + eAlign);
    int2*  csr       = (int2*)(dinv + nAlign);
    unsigned short* Xb = (unsigned short*)(csr + E);
    unsigned short* Hb = Xb + (size_t)N * H_DIM;
    int* blockSums = (int*)(Hb + (size_t)N * H_DIM);
    unsigned short* Wt1Hi = (unsigned short*)(blockSums + 256);
    unsigned short* Wt1Lo = Wt1Hi + H_DIM * H_DIM;
    unsigned short* Wt2Hi = Wt1Lo + H_DIM * H_DIM;
    unsigned short* Wt2Lo = Wt2Hi + H_DIM * H_DIM;
    unsigned short* Xhi = Wt2Lo + H_DIM * H_DIM;
    unsigned short* Xlo = Xhi + (size_t)N * H_DIM;

    int scanBlocks = (N + 1023) / 1024;   // 40 for N=40000 (<=256 supported)
    int total8 = N * H_DIM / 8;
    int xb = (total8 + 255) / 256;
    int histBlocks = (E + 255) / 256;
    int gemmBlocks = (N + 31) / 32;       // 32 nodes/block

    // ---- One memset for cnt + pooledSum (adjacent)
    hipMemsetAsync(cnt, 0, (nAlign + (size_t)G * H_DIM) * sizeof(int), stream);

    // ---- Fused histogram (FIRST) + W-split + X-split
    prep_kernel<<<histBlocks + 128 + xb, 256, 0, stream>>>(
        W1, W2, Wt1Hi, Wt1Lo, Wt2Hi, Wt2Lo, x, Xhi, Xlo, total8, histBlocks,
        col, cnt, rank, E);

    // ---- 2-dispatch scan (phase2 folded into phase3)
    scan_phase1<<<scanBlocks, 256, 0, stream>>>(cnt, blockSums, dinv, N);
    scan_phase23<<<scanBlocks, 256, 0, stream>>>(cnt, blockSums, offs, N, scanBlocks);

    // ---- FUSED scatter + layer-1 GEMM (independent; scatter latency hides
    //      under MFMA waves; scatter blocks first)
    scatter_gemm1<<<histBlocks + gemmBlocks, 256, 0, stream>>>(
        row, col, rank, dinv, offs, csr, E, histBlocks,
        Xhi, Xlo, Wt1Hi, Wt1Lo, Xb, N);

    int aggBlocks = (N + 3) / 4;          // 4 waves/block, 1 wave/node

    // ---- Layer 1 aggregation
    agg_fused<<<aggBlocks, 256, 0, stream>>>(Xb, dinv, csr, offs, b1, Hb, N);

    // ---- Layer 2 (reuse Xb for XW2)
    gemm_mfma_bf16A<<<gemmBlocks, 256, 0, stream>>>(Hb, Wt2Hi, Wt2Lo, Xb, N);
    agg_fused<<<aggBlocks, 256, 0, stream>>>(Xb, dinv, csr, offs, b2, Hb, N);

    // ---- Pool (partial sums + atomics) + head (count/divide folded in)
    pool_partial<<<(N + 63) / 64, 256, 0, stream>>>(Hb, batch, pooledSum, N);
    head_kernel<<<G, 64, 0, stream>>>(pooledSum, batch, Wfc, bfc, out, N);
}